// Round 1
// baseline (423.000 us; speedup 1.0000x reference)
//
#include <hip/hip_runtime.h>
#include <math.h>

// FPN anchor decode, fused 5 levels. B=16, IH=IW=1024.
// Outputs flat: scores (B,N,2), boxes (B,N,4), anchors (B,N,4), N=261888.
//
// Round-4 structure: vectorized 4-positions-per-thread path for levels 2-5,
// scalar tail for level 6.
//   - Levels 2..5 span flat-N [0, 261120): every level offset (0, 196608,
//     245760, 258048) and every anchor-plane size (hw >= 1024) is a multiple
//     of 1024, so a 1024-position chunk never straddles a batch, level, or
//     anchor plane. One block = 256 threads x 4 consecutive positions.
//     Loads become dwordx4 (16 B/lane, 1 KiB/wave-instruction); stores are
//     2x float4 (scores) + 8x float4 (boxes+anchors) per thread.
//   - Level 6 (hw=256, 768 pos/batch = 0.3% of work): original scalar path,
//     48 blocks of 256 positions.
//   - All global accesses nontemporal: every byte is read-once/write-once,
//     no reuse -> keep it out of L2.
// Level constants (i=2..6): h=w=1024>>i, scale=2^i, coff=0.5*(2^i-1),
// ha=wa=1024>>(6-i); aspect table hs=[ha,ha,2ha], ws=[2wa,wa,wa].

#define BATCH 16
#define NPOS  261888
#define TOTAL (BATCH * NPOS)        // 4,190,208
#define VEC_NPB     255             // 1024-pos chunks per batch (levels 2-5)
#define VEC_BLOCKS  (BATCH * VEC_NPB)   // 4080
#define TAIL_CPB    3               // level-6 256-pos chunks per batch
#define TAIL_BLOCKS (BATCH * TAIL_CPB)  // 48

typedef float f4 __attribute__((ext_vector_type(4)));
typedef float f2 __attribute__((ext_vector_type(2)));

__global__ __launch_bounds__(256) void fpn_decode_kernel(
    const float* __restrict__ cs2, const float* __restrict__ bp2,
    const float* __restrict__ cs3, const float* __restrict__ bp3,
    const float* __restrict__ cs4, const float* __restrict__ bp4,
    const float* __restrict__ cs5, const float* __restrict__ bp5,
    const float* __restrict__ cs6, const float* __restrict__ bp6,
    float* __restrict__ out)
{
    const int t   = threadIdx.x;
    const int blk = blockIdx.x;
    float* const bx = out + (size_t)TOTAL * 2;
    float* const an = out + (size_t)TOTAL * 6;
    const float FIH = 1024.f, FIW = 1024.f;

    if (blk < VEC_BLOCKS) {
        // ---- vectorized path: levels 2-5, 4 positions per thread ----
        const int b  = blk / VEC_NPB;               // batch (scalar magic-mul)
        const int n0 = (blk - b * VEC_NPB) * 1024;  // chunk base within N

        const float* cs; const float* bp;
        int off, lgw, lghw; float scale, coff, ah0;
        if (n0 < 196608)      { cs=cs2; bp=bp2; off=0;      lgw=8; lghw=16; scale=4.f;  coff=1.5f;  ah0=64.f;  }
        else if (n0 < 245760) { cs=cs3; bp=bp3; off=196608; lgw=7; lghw=14; scale=8.f;  coff=3.5f;  ah0=128.f; }
        else if (n0 < 258048) { cs=cs4; bp=bp4; off=245760; lgw=6; lghw=12; scale=16.f; coff=7.5f;  ah0=256.f; }
        else                  { cs=cs5; bp=bp5; off=258048; lgw=5; lghw=10; scale=32.f; coff=15.5f; ah0=512.f; }

        const int m0 = n0 - off;
        const int hw = 1 << lghw;
        const int a  = m0 >> lghw;                 // anchor plane 0..2 (block-uniform)
        const int r  = (m0 & (hw - 1)) + 4 * t;    // 16B-aligned within plane
        const int y  = r >> lgw;                   // r%4==0 and w%4==0 -> the 4
        const int x0 = r & ((1 << lgw) - 1);       // positions share one row

        const float ah  = (a == 2) ? 2.f * ah0 : ah0;
        const float aw  = (a == 0) ? 2.f * ah0 : ah0;
        const float cy  = scale * (float)y  + coff;
        const float cx0 = scale * (float)x0 + coff;

        const size_t csbase = ((size_t)(b * 6  + 2 * a)) * hw + r;
        const size_t bpbase = ((size_t)(b * 12 + 4 * a)) * hw + r;
        const f4 c0 = __builtin_nontemporal_load((const f4*)(cs + csbase));
        const f4 c1 = __builtin_nontemporal_load((const f4*)(cs + csbase + (size_t)hw));
        const f4 d0 = __builtin_nontemporal_load((const f4*)(bp + bpbase));
        const f4 d1 = __builtin_nontemporal_load((const f4*)(bp + bpbase + (size_t)hw));
        const f4 d2 = __builtin_nontemporal_load((const f4*)(bp + bpbase + 2 * (size_t)hw));
        const f4 d3 = __builtin_nontemporal_load((const f4*)(bp + bpbase + 3 * (size_t)hw));

        const size_t pos = (size_t)b * NPOS + n0 + 4 * t;

        // scores (B,N,2): interleave [c0,c1] per position, 2x float4
        f4 sA = { c0[0], c1[0], c0[1], c1[1] };
        f4 sB = { c0[2], c1[2], c0[3], c1[3] };
        __builtin_nontemporal_store(sA, (f4*)(out + pos * 2));
        __builtin_nontemporal_store(sB, (f4*)(out + pos * 2 + 4));

        #pragma unroll
        for (int j = 0; j < 4; ++j) {
            const float cx  = cx0 + scale * (float)j;
            const float cyc = cy + d0[j] * ah;
            const float cxc = cx + d1[j] * aw;
            const float hh  = ah * __expf(d2[j]);
            const float ww  = aw * __expf(d3[j]);
            f4 box = { fminf(fmaxf(cyc - 0.5f * hh, 0.f), FIH),
                       fminf(fmaxf(cxc - 0.5f * ww, 0.f), FIW),
                       fminf(fmaxf(cyc + 0.5f * hh, 0.f), FIH),
                       fminf(fmaxf(cxc + 0.5f * ww, 0.f), FIW) };
            __builtin_nontemporal_store(box, (f4*)(bx + (pos + j) * 4));
            f4 anc = { cy, cx, ah, aw };
            __builtin_nontemporal_store(anc, (f4*)(an + (pos + j) * 4));
        }
    } else {
        // ---- scalar tail: level 6 (hw=256), one position per thread ----
        const int blk2 = blk - VEC_BLOCKS;
        const int b = blk2 / TAIL_CPB;
        const int a = blk2 - b * TAIL_CPB;      // anchor plane == chunk index
        const int n = 261120 + (a << 8) + t;
        const int hw = 256;
        const int y = t >> 4, x = t & 15;

        const float ah = (a == 2) ? 2048.f : 1024.f;
        const float aw = (a == 0) ? 2048.f : 1024.f;
        const float cy = 64.f * (float)y + 31.5f;
        const float cx = 64.f * (float)x + 31.5f;

        const size_t csbase = ((size_t)(b * 6  + 2 * a)) * hw + t;
        const size_t bpbase = ((size_t)(b * 12 + 4 * a)) * hw + t;
        const float c0 = __builtin_nontemporal_load(cs6 + csbase);
        const float c1 = __builtin_nontemporal_load(cs6 + csbase + hw);
        const float d0 = __builtin_nontemporal_load(bp6 + bpbase);
        const float d1 = __builtin_nontemporal_load(bp6 + bpbase + hw);
        const float d2 = __builtin_nontemporal_load(bp6 + bpbase + 2 * hw);
        const float d3 = __builtin_nontemporal_load(bp6 + bpbase + 3 * hw);

        const size_t pos = (size_t)b * NPOS + n;

        f2 s = { c0, c1 };
        __builtin_nontemporal_store(s, (f2*)(out + pos * 2));

        const float cyc = cy + d0 * ah;
        const float cxc = cx + d1 * aw;
        const float hh  = ah * __expf(d2);
        const float ww  = aw * __expf(d3);
        f4 box = { fminf(fmaxf(cyc - 0.5f * hh, 0.f), FIH),
                   fminf(fmaxf(cxc - 0.5f * ww, 0.f), FIW),
                   fminf(fmaxf(cyc + 0.5f * hh, 0.f), FIH),
                   fminf(fmaxf(cxc + 0.5f * ww, 0.f), FIW) };
        __builtin_nontemporal_store(box, (f4*)(bx + pos * 4));
        f4 anc = { cy, cx, ah, aw };
        __builtin_nontemporal_store(anc, (f4*)(an + pos * 4));
    }
}

extern "C" void kernel_launch(void* const* d_in, const int* in_sizes, int n_in,
                              void* d_out, int out_size, void* d_ws, size_t ws_size,
                              hipStream_t stream) {
    const float* cs2 = (const float*)d_in[0];
    const float* bp2 = (const float*)d_in[1];
    const float* cs3 = (const float*)d_in[2];
    const float* bp3 = (const float*)d_in[3];
    const float* cs4 = (const float*)d_in[4];
    const float* bp4 = (const float*)d_in[5];
    const float* cs5 = (const float*)d_in[6];
    const float* bp5 = (const float*)d_in[7];
    const float* cs6 = (const float*)d_in[8];
    const float* bp6 = (const float*)d_in[9];
    float* out = (float*)d_out;

    const dim3 block(256);
    const dim3 grid(VEC_BLOCKS + TAIL_BLOCKS);   // 4128 blocks
    hipLaunchKernelGGL(fpn_decode_kernel, grid, block, 0, stream,
                       cs2, bp2, cs3, bp3, cs4, bp4, cs5, bp5, cs6, bp6, out);
}

// Round 2
// 259.643 us; speedup vs baseline: 1.6292x; 1.6292x over previous
//
#include <hip/hip_runtime.h>
#include <math.h>

// FPN anchor decode, fused 5 levels. B=16, IH=IW=1024.
// Outputs flat: scores (B,N,2), boxes (B,N,4), anchors (B,N,4), N=261888.
//
// Round-5 = revert to round-3/round-0 structure: one thread per position,
// no LDS, no barrier, NO nontemporal hints.
//   - Round-4 post-mortem: 4-pos/thread made box/anchor stores 64B-lane-
//     strided (25% utilization) and nt hints caused 2x HBM write
//     amplification + defeated L3 residency of the static inputs
//     (FETCH_SIZE 49MB vs ~0 expected). Reverted.
//   - Input reads: per-channel stride-1 dword loads (64 lanes x 4B = 256B
//     contiguous per wave instruction). Inputs are static across timed
//     iterations and fit in L3 (100.6 MB < 256 MB) -> mostly L3 hits.
//   - Output stores: float2 (scores) / float4 (boxes, anchors), lane-
//     contiguous -> 100% line utilization.
// Block = 256 threads = 256 consecutive positions. All level offsets
// (196608/245760/258048/261120), NPOS (=256*1023) and anchor-plane sizes
// (hw >= 256) are multiples of 256, so a block never straddles a batch,
// level, or anchor plane -> batch/level/anchor selection is wave-uniform
// (and batch/level are computed scalar from blockIdx.x).
//
// Per-level constants (i=2..6): h=w=1024>>i, offset in N, scale=2^i,
// coff=0.5*(2^i-1), ha=wa=1024>>(6-i); aspect table hs=[ha,ha,2ha],
// ws=[2wa,wa,wa].

#define BATCH 16
#define NPOS  261888
#define TOTAL (BATCH * NPOS)   // 4,190,208
#define BPB   1023             // blocks per batch = NPOS/256

__global__ __launch_bounds__(256) void fpn_decode_kernel(
    const float* __restrict__ cs2, const float* __restrict__ bp2,
    const float* __restrict__ cs3, const float* __restrict__ bp3,
    const float* __restrict__ cs4, const float* __restrict__ bp4,
    const float* __restrict__ cs5, const float* __restrict__ bp5,
    const float* __restrict__ cs6, const float* __restrict__ bp6,
    float* __restrict__ out)
{
    const int t   = threadIdx.x;
    const int blk = blockIdx.x;
    const int b   = blk / BPB;              // batch (scalar magic-mul)
    const int n0  = (blk - b * BPB) * 256;  // block's base position in N
    const int n   = n0 + t;

    // level select on scalar n0 -> wave-uniform, scalar branches
    const float* cs; const float* bp;
    int off, lgw, lghw; float scale, coff, ah0;
    if (n0 < 196608)      { cs=cs2; bp=bp2; off=0;      lgw=8; lghw=16; scale=4.f;  coff=1.5f;  ah0=64.f;   }
    else if (n0 < 245760) { cs=cs3; bp=bp3; off=196608; lgw=7; lghw=14; scale=8.f;  coff=3.5f;  ah0=128.f;  }
    else if (n0 < 258048) { cs=cs4; bp=bp4; off=245760; lgw=6; lghw=12; scale=16.f; coff=7.5f;  ah0=256.f;  }
    else if (n0 < 261120) { cs=cs5; bp=bp5; off=258048; lgw=5; lghw=10; scale=32.f; coff=15.5f; ah0=512.f;  }
    else                  { cs=cs6; bp=bp6; off=261120; lgw=4; lghw=8;  scale=64.f; coff=31.5f; ah0=1024.f; }

    const int m  = n - off;
    const int hw = 1 << lghw;
    const int a  = m >> lghw;               // anchor index 0..2 (wave-uniform)
    const int r  = m & (hw - 1);            // linear offset within plane
    const int y  = r >> lgw;
    const int x  = r & ((1 << lgw) - 1);

    // anchor h/w: hs=[ha,ha,2ha], ws=[2wa,wa,wa]; wa==ah0 since IH==IW
    const float ah = (a == 2) ? 2.f * ah0 : ah0;
    const float aw = (a == 0) ? 2.f * ah0 : ah0;
    const float cy = scale * (float)y + coff;
    const float cx = scale * (float)x + coff;

    // stride-1 coalesced dword loads (one per channel)
    const size_t csbase = ((size_t)(b * 6  + 2 * a)) * hw + r;
    const size_t bpbase = ((size_t)(b * 12 + 4 * a)) * hw + r;
    const float c0 = cs[csbase];
    const float c1 = cs[csbase + (size_t)hw];
    const float d0 = bp[bpbase];
    const float d1 = bp[bpbase + (size_t)hw];
    const float d2 = bp[bpbase + 2 * (size_t)hw];
    const float d3 = bp[bpbase + 3 * (size_t)hw];

    const size_t pos = (size_t)b * NPOS + n;

    // scores: (B,N,2) lane-contiguous float2 store
    *(float2*)(out + pos * 2) = make_float2(c0, c1);

    // decode box
    const float cyc = cy + d0 * ah;
    const float cxc = cx + d1 * aw;
    const float hh  = ah * __expf(d2);
    const float ww  = aw * __expf(d3);
    const float FIH = 1024.f, FIW = 1024.f;
    const float y1 = fminf(fmaxf(cyc - 0.5f * hh, 0.f), FIH);
    const float x1 = fminf(fmaxf(cxc - 0.5f * ww, 0.f), FIW);
    const float y2 = fminf(fmaxf(cyc + 0.5f * hh, 0.f), FIH);
    const float x2 = fminf(fmaxf(cxc + 0.5f * ww, 0.f), FIW);

    float* const bx = out + (size_t)TOTAL * 2;
    float* const an = out + (size_t)TOTAL * 6;
    *(float4*)(bx + pos * 4) = make_float4(y1, x1, y2, x2);
    *(float4*)(an + pos * 4) = make_float4(cy, cx, ah, aw);
}

extern "C" void kernel_launch(void* const* d_in, const int* in_sizes, int n_in,
                              void* d_out, int out_size, void* d_ws, size_t ws_size,
                              hipStream_t stream) {
    const float* cs2 = (const float*)d_in[0];
    const float* bp2 = (const float*)d_in[1];
    const float* cs3 = (const float*)d_in[2];
    const float* bp3 = (const float*)d_in[3];
    const float* cs4 = (const float*)d_in[4];
    const float* bp4 = (const float*)d_in[5];
    const float* cs5 = (const float*)d_in[6];
    const float* bp5 = (const float*)d_in[7];
    const float* cs6 = (const float*)d_in[8];
    const float* bp6 = (const float*)d_in[9];
    float* out = (float*)d_out;

    const dim3 block(256);
    const dim3 grid(TOTAL / 256);   // 16368 blocks, exact
    hipLaunchKernelGGL(fpn_decode_kernel, grid, block, 0, stream,
                       cs2, bp2, cs3, bp3, cs4, bp4, cs5, bp5, cs6, bp6, out);
}